// Round 3
// baseline (543.500 us; speedup 1.0000x reference)
//
#include <hip/hip_runtime.h>

#define W_ 512
#define H_ 512
#define HW (512 * 512)   // 2^18
#define P_ 20
#define B_ 8
#define TL_ 29
#define IL_ 9

// One advect step, 8 px/thread (2x float4). Also emits the motion_out copy for
// this step's two flow planes from registers (saves a separate memcpy pass).
// Carry for p>0 is read from evo_result[p-1] * 128 — exact (pow2 scaling
// commutes bit-exactly with the lerp). Stream ordering = inter-step sync.
__global__ __launch_bounds__(256) void step_kernel(
    const float* __restrict__ prev_base,   // carry source, per-batch stride prev_stride
    long prev_stride,                      // elements between batches in prev
    float prev_scale,                      // 1.0 for frames, 128.0 for evo_result readback
    const float* __restrict__ motion,      // (B, 2P, H, W)
    const float* __restrict__ intensity,   // (B, P, H, W)
    float* __restrict__ evo_result,        // (B, P, H, W)
    float* __restrict__ evo_motion,        // (B, P, H, W)
    float* __restrict__ motion_out,        // (B, 2P, H, W)
    int p)
{
    const long t    = (long)blockIdx.x * blockDim.x + threadIdx.x;
    const long base = t * 8;                 // first pixel (global over B*HW)
    const int  b    = (int)(base >> 18);     // / HW
    const int  rem0 = (int)(base & (HW - 1));
    const int  y    = rem0 >> 9;
    const int  xb   = rem0 & (W_ - 1);
    const float yf  = (float)y;

    const float* prev = prev_base + (long)b * prev_stride;

    const long mo0 = ((long)b * (2 * P_) + 2 * p) * HW + rem0;  // flow-x plane
    const long mo1 = mo0 + HW;                                   // flow-y plane
    const long io  = ((long)b * P_ + p) * HW + rem0;             // intensity / outputs

    float4 f0a = *(const float4*)(motion + mo0);
    float4 f0b = *(const float4*)(motion + mo0 + 4);
    float4 f1a = *(const float4*)(motion + mo1);
    float4 f1b = *(const float4*)(motion + mo1 + 4);
    float4 ina = *(const float4*)(intensity + io);
    float4 inb = *(const float4*)(intensity + io + 4);

    // motion_ output = pure copy, from registers
    *(float4*)(motion_out + mo0)     = f0a;
    *(float4*)(motion_out + mo0 + 4) = f0b;
    *(float4*)(motion_out + mo1)     = f1a;
    *(float4*)(motion_out + mo1 + 4) = f1b;

    const float fx[8] = {f0a.x, f0a.y, f0a.z, f0a.w, f0b.x, f0b.y, f0b.z, f0b.w};
    const float fy[8] = {f1a.x, f1a.y, f1a.z, f1a.w, f1b.x, f1b.y, f1b.z, f1b.w};
    const float iv[8] = {ina.x, ina.y, ina.z, ina.w, inb.x, inb.y, inb.z, inb.w};
    float res[8], bil[8];

    #pragma unroll
    for (int j = 0; j < 8; ++j) {
        float cx = fminf(fmaxf((float)(xb + j) + fx[j], 0.0f), 511.0f);
        float cy = fminf(fmaxf(yf + fy[j], 0.0f), 511.0f);

        float x0f = floorf(cx), y0f = floorf(cy);
        float wx = cx - x0f, wy = cy - y0f;
        int x0 = (int)x0f, y0 = (int)y0f;
        int x1 = min(x0 + 1, W_ - 1), y1 = min(y0 + 1, H_ - 1);

        const float* r0 = prev + y0 * W_;
        const float* r1 = prev + y1 * W_;
        float v00 = r0[x0], v01 = r0[x1];
        float v10 = r1[x0], v11 = r1[x1];
        bil[j] = prev_scale * ((1.0f - wy) * ((1.0f - wx) * v00 + wx * v01)
                                     + wy  * ((1.0f - wx) * v10 + wx * v11));

        int xi = (int)rintf(cx);   // half-to-even == jnp.round
        int yi = (int)rintf(cy);
        res[j] = (prev_scale * prev[yi * W_ + xi] + iv[j]) * 0.0078125f;  // /128 exact
    }

    *(float4*)(evo_result + io)     = make_float4(res[0], res[1], res[2], res[3]);
    *(float4*)(evo_result + io + 4) = make_float4(res[4], res[5], res[6], res[7]);
    *(float4*)(evo_motion + io)     = make_float4(bil[0], bil[1], bil[2], bil[3]);
    *(float4*)(evo_motion + io + 4) = make_float4(bil[4], bil[5], bil[6], bil[7]);
}

extern "C" void kernel_launch(void* const* d_in, const int* in_sizes, int n_in,
                              void* d_out, int out_size, void* d_ws, size_t ws_size,
                              hipStream_t stream)
{
    const float* frames    = (const float*)d_in[0];  // (B, TL, H, W, 1)
    const float* motion    = (const float*)d_in[1];  // (B, 2P, H, W)
    const float* intensity = (const float*)d_in[2];  // (B, P, H, W)

    float* out        = (float*)d_out;
    float* evo_result = out;                          // B*P*HW
    float* evo_motion = out + (long)B_ * P_ * HW;     // B*P*HW
    float* motion_out = out + 2L * B_ * P_ * HW;      // B*2P*HW

    const int threads = 256;
    const int blocks  = (B_ * HW / 8) / threads;      // 1024

    // step 0: carry = frames[:, IL-1, :, :, 0]
    step_kernel<<<blocks, threads, 0, stream>>>(
        frames + (long)(IL_ - 1) * HW, (long)TL_ * HW, 1.0f,
        motion, intensity, evo_result, evo_motion, motion_out, 0);

    // steps 1..P-1: carry = evo_result[:, p-1] * 128 (exact)
    for (int p = 1; p < P_; ++p) {
        step_kernel<<<blocks, threads, 0, stream>>>(
            evo_result + (long)(p - 1) * HW, (long)P_ * HW, 128.0f,
            motion, intensity, evo_result, evo_motion, motion_out, p);
    }
}